// Round 21
// baseline (147.540 us; speedup 1.0000x reference)
//
#include <hip/hip_runtime.h>
#include <hip/hip_bf16.h>
#include <stdint.h>

typedef unsigned short u16;
typedef unsigned int u32;
typedef short s16x8 __attribute__((ext_vector_type(8)));
typedef short s16x4 __attribute__((ext_vector_type(4)));
typedef float f32x4 __attribute__((ext_vector_type(4)));

#define MFMA(a, b, c) __builtin_amdgcn_mfma_f32_16x16x32_bf16((a), (b), (c), 0, 0, 0)

__device__ __forceinline__ float bf2f(u16 h) {
  u32 u = ((u32)h) << 16;
  float f;
  __builtin_memcpy(&f, &u, 4);
  return f;
}

__device__ __forceinline__ u16 f2bf_rte(float f) {
  __hip_bfloat16 h = __float2bfloat16(f);
  u16 u;
  __builtin_memcpy(&u, &h, 2);
  return u;
}

__device__ __forceinline__ void gload16(const u16* g, u16* l) {
  __builtin_amdgcn_global_load_lds((const __attribute__((address_space(1))) u32*)g,
                                   (__attribute__((address_space(3))) u32*)l, 16, 0, 0);
}

// ---------------- fused prep: q_s->bf16 | pos->packed bf16 | W^T->bf16 ----------------
__global__ __launch_bounds__(256) void k_prep(const float* __restrict__ q_s,
                                              const float* __restrict__ pos,
                                              const float* __restrict__ W0,
                                              const float* __restrict__ W1,
                                              const float* __restrict__ W2,
                                              const float* __restrict__ W3,
                                              u16* __restrict__ Xbf,
                                              u16* __restrict__ Pp,
                                              u16* __restrict__ WT) {
  __shared__ u16 tile[64][65];
  const int b = blockIdx.x;
  const int t = threadIdx.x;
  if (b < 2048) {
    const int i = b * 256 + t;
    const f32x4* p = (const f32x4*)(q_s + (size_t)i * 8);
    f32x4 a = p[0], bb = p[1];
    s16x8 o;
    for (int k = 0; k < 4; ++k) o[k] = (short)f2bf_rte(a[k]);
    for (int k = 0; k < 4; ++k) o[4 + k] = (short)f2bf_rte(bb[k]);
    *(s16x8*)(Xbf + (size_t)i * 8) = o;
  } else if (b < 3072) {
    const int pb = b - 2048;
    const int bh = pb >> 5, bx = pb & 31;
    const int bq = bh >> 4, h = bh & 15;
    const int n = bx * 64 + (t >> 2);
    const int d0 = (t & 3) * 16;
    const float* src = &pos[((size_t)(bq * 2048 + n)) * 1024 + h * 64 + d0];
    u16* dst = &Pp[((size_t)bh * 2048 + n) * 64 + d0];
    f32x4 a = *(const f32x4*)src;
    f32x4 bq4 = *(const f32x4*)(src + 4);
    f32x4 c = *(const f32x4*)(src + 8);
    f32x4 dq = *(const f32x4*)(src + 12);
    s16x8 o0, o1;
    for (int i = 0; i < 4; ++i) {
      o0[i] = (short)f2bf_rte(a[i]);
      o0[4 + i] = (short)f2bf_rte(bq4[i]);
      o1[i] = (short)f2bf_rte(c[i]);
      o1[4 + i] = (short)f2bf_rte(dq[i]);
    }
    *(s16x8*)dst = o0;
    *(s16x8*)(dst + 8) = o1;
  } else {
    const int wb = b - 3072;
    const int z = wb >> 8, r2 = wb & 255;
    const int bx = r2 & 15, by = r2 >> 4;
    const float* in = (z == 0) ? W0 : (z == 1) ? W1 : (z == 2) ? W2 : W3;
    u16* o = WT + (size_t)z * 1024 * 1024;
    const int tx = t & 63, ty = t >> 6;
    const int r0 = by * 64, c0 = bx * 64;
    for (int rr = 0; rr < 16; ++rr) {
      int row = rr * 4 + ty;
      tile[row][tx] = f2bf_rte(in[(size_t)(r0 + row) * 1024 + c0 + tx]);
    }
    __syncthreads();
    for (int rr = 0; rr < 16; ++rr) {
      int row = rr * 4 + ty;
      o[(size_t)(c0 + row) * 1024 + r0 + tx] = tile[tx][row];
    }
  }
}

// ---------------- transpose V [bh][2048][64] -> Vt[bh][64][2048] ----------------
__global__ __launch_bounds__(256) void k_transpose_v(const u16* __restrict__ V,
                                                     u16* __restrict__ Vt) {
  __shared__ u16 tile[64][65];
  const int t = threadIdx.x, tx = t & 63, ty = t >> 6;
  const int j0 = blockIdx.x * 64;
  const int bh = blockIdx.y;
  const u16* src = V + (size_t)bh * 2048 * 64;
  u16* dst = Vt + (size_t)bh * 64 * 2048;
  for (int rr = 0; rr < 16; ++rr) {
    int row = rr * 4 + ty;
    tile[row][tx] = src[(size_t)(j0 + row) * 64 + tx];
  }
  __syncthreads();
  for (int rr = 0; rr < 16; ++rr) {
    int d = rr * 4 + ty;
    dst[(size_t)d * 2048 + j0 + tx] = tile[tx][d];
  }
}

// ---------------- fused QKV GEMM: 3-buffer counted-vmcnt pipeline ----------------
__global__ __launch_bounds__(256) void k_qkv_gemm(const u16* __restrict__ X,
                                                  const u16* __restrict__ WT,
                                                  const u16* __restrict__ Pp,
                                                  u16* __restrict__ Qh,
                                                  u16* __restrict__ Kh,
                                                  u16* __restrict__ Vh) {
  __shared__ u16 As[3][4096];
  __shared__ u16 Bs[3][4096];
  const int t = threadIdx.x;
  const int lane = t & 63, wid = t >> 6;
  const int wr = wid >> 1, wc = wid & 1;
  const int g = lane >> 4, lr = lane & 15;
  const int lin = blockIdx.y * 24 + blockIdx.x;
  const int swz = (lin & 7) * 96 + (lin >> 3);
  const int m0 = (swz / 24) * 128, n0 = (swz % 24) * 128;

  const int srcRow = t >> 2;
  const int srcKsw = ((t & 3) * 8) ^ (((t >> 3) & 3) << 3);
  const u16* aSrc = &X[(size_t)(m0 + srcRow) * 1024 + srcKsw];
  const u16* bSrc = &WT[(size_t)(n0 + srcRow) * 1024 + srcKsw];

  const int csw = (g * 8) ^ (((lr >> 1) & 3) << 3);

  f32x4 acc[4][4] = {};

#define QKV_STAGE(buf, k0)                                   \
  {                                                          \
    gload16(aSrc + (k0), &As[buf][wid * 512]);               \
    gload16(aSrc + 65536 + (k0), &As[buf][wid * 512 + 2048]);\
    gload16(bSrc + (k0), &Bs[buf][wid * 512]);               \
    gload16(bSrc + 65536 + (k0), &Bs[buf][wid * 512 + 2048]);\
  }

  QKV_STAGE(0, 0);
  QKV_STAGE(1, 32);
  QKV_STAGE(2, 64);
  for (int k = 0; k < 32; ++k) {
    if (k < 30) {
      asm volatile("s_waitcnt vmcnt(8)" ::: "memory");
    } else if (k == 30) {
      asm volatile("s_waitcnt vmcnt(4)" ::: "memory");
    } else {
      asm volatile("s_waitcnt vmcnt(0)" ::: "memory");
    }
    __builtin_amdgcn_sched_barrier(0);
    __builtin_amdgcn_s_barrier();
    const int cur = k % 3;
    s16x8 a[4], b[4];
#pragma unroll
    for (int mi = 0; mi < 4; ++mi)
      a[mi] = *(const s16x8*)&As[cur][(wr * 64 + mi * 16 + lr) * 32 + csw];
#pragma unroll
    for (int nj = 0; nj < 4; ++nj)
      b[nj] = *(const s16x8*)&Bs[cur][(wc * 64 + nj * 16 + lr) * 32 + csw];
#pragma unroll
    for (int mi = 0; mi < 4; ++mi)
#pragma unroll
      for (int nj = 0; nj < 4; ++nj)
        acc[mi][nj] = MFMA(a[mi], b[nj], acc[mi][nj]);
    __builtin_amdgcn_s_barrier();
    if (k < 29) QKV_STAGE(cur, (k + 3) * 32);
  }
#undef QKV_STAGE

  const float QSCALE = 0.125f * 1.44269504f;
  for (int mi = 0; mi < 4; ++mi) {
    for (int nj = 0; nj < 4; ++nj) {
      const int n_g = n0 + wc * 64 + nj * 16 + lr;
      const int buf = n_g >> 10;       // 0=Q 1=K 2=V
      const int col = n_g & 1023;
      const int h = col >> 6, d = col & 63;
      u16* dst = (buf == 0) ? Qh : ((buf == 1) ? Kh : Vh);
      for (int r = 0; r < 4; ++r) {
        const int row = m0 + wr * 64 + mi * 16 + g * 4 + r;  // 0..4095
        const int b = row >> 11, n = row & 2047;
        const size_t off = (size_t)((b * 16 + h) * 2048 + n) * 64 + d;
        float v = acc[mi][nj][r];
        if (buf == 1) v += bf2f(Pp[off]);
        if (buf == 0) v *= QSCALE;
        dst[off] = f2bf_rte(v);
      }
    }
  }
}

// ---------------- flash attention: j-tile 128, 2-buffer gload_lds, permlane P ----------------
__global__ __launch_bounds__(512, 4) void k_attn(const u16* __restrict__ Qh,
                                                 const u16* __restrict__ Kh,
                                                 const u16* __restrict__ Vt,
                                                 u16* __restrict__ Oh) {
  const int t = threadIdx.x, lane = t & 63, wid = t >> 6;  // wid 0..7
  const int g = lane >> 4, lr = lane & 15;
  const int hid = blockIdx.x;
  const int lid = (hid & 7) * 64 + (hid >> 3);   // bijective XCD swizzle (512 % 8 == 0)
  const int bh = lid >> 4, itile = lid & 15;
  const int i0 = itile * 128 + wid * 16;         // this wave's 16 Q rows

  __shared__ char Ks[2][16384];   // K tile [128 j][128B], dbuf, swizzled via source
  __shared__ char Vs[2][16384];   // V tile [64 d][256B], dbuf, swizzled via source

  const u16* Qp = Qh + (size_t)bh * 2048 * 64;
  const u16* Kp = Kh + (size_t)bh * 2048 * 64;
  const u16* Vp = Vt + (size_t)bh * 64 * 2048;

  s16x8 aq[2];
  aq[0] = *(const s16x8*)&Qp[(size_t)(i0 + lr) * 64 + g * 8];
  aq[1] = *(const s16x8*)&Qp[(size_t)(i0 + lr) * 64 + 32 + g * 8];

  f32x4 oa[4] = {};
  float ms = -1e30f, ls = 0.f;

  // staging (linear dest; source pre-swizzled with byte ^= (row&7)<<4)
  const int kRow = t >> 3;                 // 0..63 (call1: +64; (row+64)&7==row&7)
  const int kCh = (t & 7) * 16;
  const int kChS = kCh ^ ((kRow & 7) << 4);
  const u16* kS0 = &Kp[(size_t)kRow * 64 + (kChS >> 1)];
  const u16* kS1 = &Kp[(size_t)(kRow + 64) * 64 + (kChS >> 1)];
  const int vRow = t >> 4;                 // 0..31 (call1: +32; (row+32)&7==row&7)
  const int vCh = (t & 15) * 16;
  const int vChS = vCh ^ ((vRow & 7) << 4);
  const u16* vS0 = &Vp[(size_t)vRow * 2048 + (vChS >> 1)];
  const u16* vS1 = &Vp[(size_t)(vRow + 32) * 2048 + (vChS >> 1)];

#define ATTN_STAGE(p, BUF)                                          \
  {                                                                 \
    gload16(kS0 + (size_t)(p) * 8192, (u16*)Ks[BUF] + wid * 512);   \
    gload16(kS1 + (size_t)(p) * 8192, (u16*)Ks[BUF] + 4096 + wid * 512); \
    gload16(vS0 + (size_t)(p) * 128, (u16*)Vs[BUF] + wid * 512);    \
    gload16(vS1 + (size_t)(p) * 128, (u16*)Vs[BUF] + 4096 + wid * 512); \
  }

#define ATTN_BODY(BUF)                                                         \
  {                                                                            \
    const char* Kc = Ks[BUF];                                                  \
    const char* Vc = Vs[BUF];                                                  \
    f32x4 s[8];                                                                \
    _Pragma("unroll") for (int jf = 0; jf < 8; ++jf) {                         \
      const int row = jf * 16 + lr;                                            \
      const int bw = (row & 7) << 4;                                           \
      s16x8 bk0 = *(const s16x8*)(Kc + ((row * 128 + g * 16) ^ bw));           \
      s16x8 bk1 = *(const s16x8*)(Kc + ((row * 128 + 64 + g * 16) ^ bw));      \
      f32x4 z = {};                                                            \
      z = MFMA(bk0, aq[0], z);                                                 \
      s[jf] = MFMA(bk1, aq[1], z);                                             \
    }                                                                          \
    float mj[8];                                                               \
    _Pragma("unroll") for (int jf = 0; jf < 8; ++jf)                           \
        mj[jf] = fmaxf(fmaxf(s[jf][0], s[jf][1]), fmaxf(s[jf][2], s[jf][3]));  \
    float tl = fmaxf(fmaxf(fmaxf(mj[0], mj[1]), fmaxf(mj[2], mj[3])),          \
                     fmaxf(fmaxf(mj[4], mj[5]), fmaxf(mj[6], mj[7])));         \
    if (!__all(tl <= ms + 8.f)) {                                              \
      float tm = fmaxf(tl, __shfl_xor(tl, 16, 64));                            \
      tm = fmaxf(tm, __shfl_xor(tm, 32, 64));                                  \
      float mn = fmaxf(ms, tm);                                                \
      float al = __builtin_amdgcn_exp2f(ms - mn);                              \
      ls *= al;                                                                \
      ms = mn;                                                                 \
      _Pragma("unroll") for (int r = 0; r < 4; ++r) {                          \
        float ab = __shfl(al, g * 4 + r, 64);                                  \
        _Pragma("unroll") for (int df = 0; df < 4; ++df) oa[df][r] *= ab;      \
      }                                                                        \
    }                                                                          \
    float pj[8];                                                               \
    _Pragma("unroll") for (int jf = 0; jf < 8; ++jf) {                         \
      _Pragma("unroll") for (int r = 0; r < 4; ++r)                            \
          s[jf][r] = __builtin_amdgcn_exp2f(s[jf][r] - ms);                    \
      pj[jf] = (s[jf][0] + s[jf][1]) + (s[jf][2] + s[jf][3]);                  \
    }                                                                          \
    ls += ((pj[0] + pj[1]) + (pj[2] + pj[3])) +                                \
          ((pj[4] + pj[5]) + (pj[6] + pj[7]));                                 \
    u32 pk[8][2];                                                              \
    _Pragma("unroll") for (int jf = 0; jf < 8; ++jf) {                         \
      asm("v_cvt_pk_bf16_f32 %0, %1, %2"                                       \
          : "=v"(pk[jf][0]) : "v"(s[jf][0]), "v"(s[jf][1]));                   \
      asm("v_cvt_pk_bf16_f32 %0, %1, %2"                                       \
          : "=v"(pk[jf][1]) : "v"(s[jf][2]), "v"(s[jf][3]));                   \
    }                                                                          \
    s16x8 pa[4];                                                               \
    _Pragma("unroll") for (int c = 0; c < 4; ++c) {                            \
      u32 w_[4];                                                               \
      _Pragma("unroll") for (int wl = 0; wl < 2; ++wl) {                       \
        u32 A = pk[2 * c][wl], B = pk[2 * c + 1][wl];                          \
        asm("v_permlane32_swap_b32 %0, %1" : "+v"(A), "+v"(B));                \
        asm("v_permlane16_swap_b32 %0, %1" : "+v"(A), "+v"(B));                \
        w_[wl] = A;                                                            \
        w_[2 + wl] = B;                                                        \
      }                                                                        \
      __builtin_memcpy(&pa[c], w_, 16);                                        \
    }                                                                          \
    _Pragma("unroll") for (int df = 0; df < 4; ++df) {                         \
      const int row = df * 16 + lr;                                            \
      const int bw = (row & 7) << 4;                                           \
      _Pragma("unroll") for (int c = 0; c < 4; ++c) {                          \
        s16x8 bv = *(const s16x8*)(Vc + ((row * 256 + c * 64 + g * 16) ^ bw)); \
        oa[df] = MFMA(pa[c], bv, oa[df]);                                      \
      }                                                                        \
    }                                                                          \
  }

  ATTN_STAGE(0, 0);

  for (int th = 0; th < 8; ++th) {
#pragma unroll
    for (int ti = 0; ti < 2; ++ti) {
      const int tt = th * 2 + ti;
      asm volatile("s_waitcnt vmcnt(0)" ::: "memory");
      __builtin_amdgcn_sched_barrier(0);
      __builtin_amdgcn_s_barrier();
      if (tt < 15) ATTN_STAGE(tt + 1, ti ^ 1);
      ATTN_BODY(ti);
    }
  }
#undef ATTN_BODY
#undef ATTN_STAGE

  // final l: cross-g reduce, then broadcast per accumulator row
  ls += __shfl_xor(ls, 16, 64);
  ls += __shfl_xor(ls, 32, 64);
  float lb[4];
#pragma unroll
  for (int r = 0; r < 4; ++r) lb[r] = __shfl(ls, g * 4 + r, 64);

  u16* Op = Oh + (size_t)bh * 2048 * 64;
#pragma unroll
  for (int df = 0; df < 4; ++df)
#pragma unroll
    for (int r = 0; r < 4; ++r) {
      const int row0 = i0 + g * 4 + r;
      Op[(size_t)row0 * 64 + df * 16 + lr] = f2bf_rte(oa[df][r] / lb[r]);
    }
}

// ---------------- out GEMM: 3-buffer pipeline; bf16 residual; bf16 X out ----------------
__global__ __launch_bounds__(256) void k_out_gemm(const u16* __restrict__ Oh,
                                                  const u16* __restrict__ WTo,
                                                  const float* __restrict__ bo,
                                                  const u16* __restrict__ qsb,
                                                  u16* __restrict__ X) {
  __shared__ u16 As[3][4096];
  __shared__ u16 Bs[3][4096];
  const int t = threadIdx.x;
  const int lane = t & 63, wid = t >> 6;
  const int wr = wid >> 1, wc = wid & 1;
  const int g = lane >> 4, lr = lane & 15;
  const int lin = blockIdx.y * 8 + blockIdx.x;
  const int swz = (lin & 7) * 32 + (lin >> 3);
  const int m0 = (swz / 8) * 128, n0 = (swz % 8) * 128;

  const int srcRow = t >> 2;
  const int srcKsw = ((t & 3) * 8) ^ (((t >> 3) & 3) << 3);
  const int rg = m0 + srcRow, bb0 = rg >> 11, nn0 = rg & 2047;
  const int rg2 = rg + 64, bb2 = rg2 >> 11, nn2 = rg2 & 2047;
  const u16* bSrc = &WTo[(size_t)(n0 + srcRow) * 1024 + srcKsw];
  const int csw = (g * 8) ^ (((lr >> 1) & 3) << 3);

  f32x4 acc[4][4] = {};

#define OUT_STAGE(buf, k0)                                                        \
  {                                                                               \
    const int h_ = (k0) >> 6, d_ = ((k0) & 63) + srcKsw;                          \
    gload16(&Oh[((size_t)(bb0 * 16 + h_) * 2048 + nn0) * 64 + d_],                \
            &As[buf][wid * 512]);                                                 \
    gload16(&Oh[((size_t)(bb2 * 16 + h_) * 2048 + nn2) * 64 + d_],                \
            &As[buf][wid * 512 + 2048]);                                          \
    gload16(bSrc + (k0), &Bs[buf][wid * 512]);                                    \
    gload16(bSrc + 65536 + (k0), &Bs[buf][wid * 512 + 2048]);                     \
  }

  OUT_STAGE(0, 0);
  OUT_STAGE(1, 32);
  OUT_STAGE(2, 64);
  for (int k = 0; k < 32; ++k) {
    if (k < 30) {
      asm volatile("s_waitcnt vmcnt(8)" ::: "memory");
    } else if (k == 30) {
      asm volatile("s_waitcnt vmcnt(4)" ::: "memory");
    } else {
      asm volatile("s_waitcnt vmcnt(0)" ::: "memory");
    }
    __builtin_amdgcn_sched_barrier(0);
    __builtin_amdgcn_s_barrier();
    const int cur = k % 3;
    s16x8 a[4], b[4];
#pragma unroll
    for (int mi = 0; mi < 4; ++mi)
      a[mi] = *(const s16x8*)&As[cur][(wr * 64 + mi * 16 + lr) * 32 + csw];
#pragma unroll
    for (int nj = 0; nj < 4; ++nj)
      b[nj] = *(const s16x8*)&Bs[cur][(wc * 64 + nj * 16 + lr) * 32 + csw];
#pragma unroll
    for (int mi = 0; mi < 4; ++mi)
#pragma unroll
      for (int nj = 0; nj < 4; ++nj)
        acc[mi][nj] = MFMA(a[mi], b[nj], acc[mi][nj]);
    __builtin_amdgcn_s_barrier();
    if (k < 29) OUT_STAGE(cur, (k + 3) * 32);
  }
#undef OUT_STAGE

  for (int mi = 0; mi < 4; ++mi) {
    for (int nj = 0; nj < 4; ++nj) {
      const int col = n0 + wc * 64 + nj * 16 + lr;
      for (int r = 0; r < 4; ++r) {
        const int row = m0 + wr * 64 + mi * 16 + g * 4 + r;
        float v = acc[mi][nj][r] + bo[col] + bf2f(qsb[(size_t)row * 1024 + col]);
        X[(size_t)row * 1024 + col] = f2bf_rte(v);
      }
    }
  }
}

// ---------------- LayerNorm rows of 1024 (bf16 in, f32 out) ----------------
__global__ __launch_bounds__(256) void k_ln(const u16* __restrict__ X,
                                            const float* __restrict__ gg,
                                            const float* __restrict__ bb,
                                            float* __restrict__ out) {
  const int row = blockIdx.x, t = threadIdx.x;
  const int wid = t >> 6, lane = t & 63;
  const u16* xr = X + (size_t)row * 1024;
  s16x4 xv = *(const s16x4*)&xr[t * 4];
  float x[4];
  for (int i = 0; i < 4; ++i) x[i] = bf2f((u16)xv[i]);
  float s1 = (x[0] + x[1]) + (x[2] + x[3]);
  float s2 = (x[0] * x[0] + x[1] * x[1]) + (x[2] * x[2] + x[3] * x[3]);
  for (int off = 32; off > 0; off >>= 1) {
    s1 += __shfl_down(s1, off, 64);
    s2 += __shfl_down(s2, off, 64);
  }
  __shared__ float red[2][4];
  if (lane == 0) { red[0][wid] = s1; red[1][wid] = s2; }
  __syncthreads();
  s1 = red[0][0] + red[0][1] + red[0][2] + red[0][3];
  s2 = red[1][0] + red[1][1] + red[1][2] + red[1][3];
  const float mu = s1 * (1.f / 1024.f);
  const float var = s2 * (1.f / 1024.f) - mu * mu;
  const float rstd = rsqrtf(var + 1e-5f);
  f32x4 gv = *(const f32x4*)&gg[t * 4];
  f32x4 bv = *(const f32x4*)&bb[t * 4];
  f32x4 ov;
  for (int i = 0; i < 4; ++i) ov[i] = (x[i] - mu) * rstd * gv[i] + bv[i];
  *(f32x4*)&out[(size_t)row * 1024 + t * 4] = ov;
}

extern "C" void kernel_launch(void* const* d_in, const int* in_sizes, int n_in,
                              void* d_out, int out_size, void* d_ws, size_t ws_size,
                              hipStream_t stream) {
  (void)in_sizes; (void)n_in; (void)out_size; (void)ws_size;
  const float* q_s = (const float*)d_in[0];
  const float* pos = (const float*)d_in[1];
  const float* Wq = (const float*)d_in[2];
  const float* Wk = (const float*)d_in[3];
  const float* Wv = (const float*)d_in[4];
  const float* Wo = (const float*)d_in[5];
  const float* bo = (const float*)d_in[6];
  const float* lng = (const float*)d_in[7];
  const float* lnb = (const float*)d_in[8];
  float* out = (float*)d_out;

  u16* ws = (u16*)d_ws;
  const size_t MB1 = 1024 * 1024;  // elements
  u16* WT  = ws;                   // 4 x 1M bf16 (Wq^T,Wk^T,Wv^T,Wo^T)
  u16* Xbf = ws + 4 * MB1;         // q_s as bf16
  u16* Qh  = Xbf + 4 * MB1;        // [32][2048][64]
  u16* Kh  = Qh + 4 * MB1;
  u16* Vh  = Kh + 4 * MB1;
  u16* Vt  = Vh + 4 * MB1;         // [32][64][2048]
  u16* Oh  = Vt + 4 * MB1;         // [32][2048][64]
  u16* Pp  = Oh;                   // bf16 packed pos, aliases Oh (dead until attn)
  u16* Xb  = Qh;                   // bf16 pre-LN x, aliases Qh (dead after attn)

  dim3 blk(256);
  k_prep<<<dim3(4096), blk, 0, stream>>>(q_s, pos, Wq, Wk, Wv, Wo, Xbf, Pp, WT);
  k_qkv_gemm<<<dim3(24, 32), blk, 0, stream>>>(Xbf, WT, Pp, Qh, Kh, Vh);
  k_transpose_v<<<dim3(32, 32), blk, 0, stream>>>(Vh, Vt);
  k_attn<<<dim3(512), dim3(512), 0, stream>>>(Qh, Kh, Vt, Oh);
  k_out_gemm<<<dim3(8, 32), blk, 0, stream>>>(Oh, WT + 3 * MB1, bo, Xbf, Xb);
  k_ln<<<4096, blk, 0, stream>>>(Xb, lng, lnb, out);
}

// Round 22
// 142.479 us; speedup vs baseline: 1.0355x; 1.0355x over previous
//
#include <hip/hip_runtime.h>
#include <hip/hip_bf16.h>
#include <stdint.h>

typedef unsigned short u16;
typedef unsigned int u32;
typedef short s16x8 __attribute__((ext_vector_type(8)));
typedef short s16x4 __attribute__((ext_vector_type(4)));
typedef float f32x4 __attribute__((ext_vector_type(4)));

#define MFMA(a, b, c) __builtin_amdgcn_mfma_f32_16x16x32_bf16((a), (b), (c), 0, 0, 0)

__device__ __forceinline__ float bf2f(u16 h) {
  u32 u = ((u32)h) << 16;
  float f;
  __builtin_memcpy(&f, &u, 4);
  return f;
}

__device__ __forceinline__ u16 f2bf_rte(float f) {
  __hip_bfloat16 h = __float2bfloat16(f);
  u16 u;
  __builtin_memcpy(&u, &h, 2);
  return u;
}

__device__ __forceinline__ void gload16(const u16* g, u16* l) {
  __builtin_amdgcn_global_load_lds((const __attribute__((address_space(1))) u32*)g,
                                   (__attribute__((address_space(3))) u32*)l, 16, 0, 0);
}

// ---------------- fused prep: q_s->bf16 | pos->packed bf16 | W^T->bf16 ----------------
__global__ __launch_bounds__(256) void k_prep(const float* __restrict__ q_s,
                                              const float* __restrict__ pos,
                                              const float* __restrict__ W0,
                                              const float* __restrict__ W1,
                                              const float* __restrict__ W2,
                                              const float* __restrict__ W3,
                                              u16* __restrict__ Xbf,
                                              u16* __restrict__ Pp,
                                              u16* __restrict__ WT) {
  __shared__ u16 tile[64][65];
  const int b = blockIdx.x;
  const int t = threadIdx.x;
  if (b < 2048) {
    const int i = b * 256 + t;
    const f32x4* p = (const f32x4*)(q_s + (size_t)i * 8);
    f32x4 a = p[0], bb = p[1];
    s16x8 o;
    for (int k = 0; k < 4; ++k) o[k] = (short)f2bf_rte(a[k]);
    for (int k = 0; k < 4; ++k) o[4 + k] = (short)f2bf_rte(bb[k]);
    *(s16x8*)(Xbf + (size_t)i * 8) = o;
  } else if (b < 3072) {
    const int pb = b - 2048;
    const int bh = pb >> 5, bx = pb & 31;
    const int bq = bh >> 4, h = bh & 15;
    const int n = bx * 64 + (t >> 2);
    const int d0 = (t & 3) * 16;
    const float* src = &pos[((size_t)(bq * 2048 + n)) * 1024 + h * 64 + d0];
    u16* dst = &Pp[((size_t)bh * 2048 + n) * 64 + d0];
    f32x4 a = *(const f32x4*)src;
    f32x4 bq4 = *(const f32x4*)(src + 4);
    f32x4 c = *(const f32x4*)(src + 8);
    f32x4 dq = *(const f32x4*)(src + 12);
    s16x8 o0, o1;
    for (int i = 0; i < 4; ++i) {
      o0[i] = (short)f2bf_rte(a[i]);
      o0[4 + i] = (short)f2bf_rte(bq4[i]);
      o1[i] = (short)f2bf_rte(c[i]);
      o1[4 + i] = (short)f2bf_rte(dq[i]);
    }
    *(s16x8*)dst = o0;
    *(s16x8*)(dst + 8) = o1;
  } else {
    const int wb = b - 3072;
    const int z = wb >> 8, r2 = wb & 255;
    const int bx = r2 & 15, by = r2 >> 4;
    const float* in = (z == 0) ? W0 : (z == 1) ? W1 : (z == 2) ? W2 : W3;
    u16* o = WT + (size_t)z * 1024 * 1024;
    const int tx = t & 63, ty = t >> 6;
    const int r0 = by * 64, c0 = bx * 64;
    for (int rr = 0; rr < 16; ++rr) {
      int row = rr * 4 + ty;
      tile[row][tx] = f2bf_rte(in[(size_t)(r0 + row) * 1024 + c0 + tx]);
    }
    __syncthreads();
    for (int rr = 0; rr < 16; ++rr) {
      int row = rr * 4 + ty;
      o[(size_t)(c0 + row) * 1024 + r0 + tx] = tile[tx][row];
    }
  }
}

// ---------------- transpose V [bh][2048][64] -> Vt[bh][64][2048] ----------------
__global__ __launch_bounds__(256) void k_transpose_v(const u16* __restrict__ V,
                                                     u16* __restrict__ Vt) {
  __shared__ u16 tile[64][65];
  const int t = threadIdx.x, tx = t & 63, ty = t >> 6;
  const int j0 = blockIdx.x * 64;
  const int bh = blockIdx.y;
  const u16* src = V + (size_t)bh * 2048 * 64;
  u16* dst = Vt + (size_t)bh * 64 * 2048;
  for (int rr = 0; rr < 16; ++rr) {
    int row = rr * 4 + ty;
    tile[row][tx] = src[(size_t)(j0 + row) * 64 + tx];
  }
  __syncthreads();
  for (int rr = 0; rr < 16; ++rr) {
    int d = rr * 4 + ty;
    dst[(size_t)d * 2048 + j0 + tx] = tile[tx][d];
  }
}

// ---------------- fused QKV GEMM: 3-buffer counted-vmcnt pipeline ----------------
__global__ __launch_bounds__(256) void k_qkv_gemm(const u16* __restrict__ X,
                                                  const u16* __restrict__ WT,
                                                  const u16* __restrict__ Pp,
                                                  u16* __restrict__ Qh,
                                                  u16* __restrict__ Kh,
                                                  u16* __restrict__ Vh) {
  __shared__ u16 As[3][4096];
  __shared__ u16 Bs[3][4096];
  const int t = threadIdx.x;
  const int lane = t & 63, wid = t >> 6;
  const int wr = wid >> 1, wc = wid & 1;
  const int g = lane >> 4, lr = lane & 15;
  const int lin = blockIdx.y * 24 + blockIdx.x;
  const int swz = (lin & 7) * 96 + (lin >> 3);
  const int m0 = (swz / 24) * 128, n0 = (swz % 24) * 128;

  const int srcRow = t >> 2;
  const int srcKsw = ((t & 3) * 8) ^ (((t >> 3) & 3) << 3);
  const u16* aSrc = &X[(size_t)(m0 + srcRow) * 1024 + srcKsw];
  const u16* bSrc = &WT[(size_t)(n0 + srcRow) * 1024 + srcKsw];

  const int csw = (g * 8) ^ (((lr >> 1) & 3) << 3);

  f32x4 acc[4][4] = {};

#define QKV_STAGE(buf, k0)                                   \
  {                                                          \
    gload16(aSrc + (k0), &As[buf][wid * 512]);               \
    gload16(aSrc + 65536 + (k0), &As[buf][wid * 512 + 2048]);\
    gload16(bSrc + (k0), &Bs[buf][wid * 512]);               \
    gload16(bSrc + 65536 + (k0), &Bs[buf][wid * 512 + 2048]);\
  }

  QKV_STAGE(0, 0);
  QKV_STAGE(1, 32);
  QKV_STAGE(2, 64);
  for (int k = 0; k < 32; ++k) {
    if (k < 30) {
      asm volatile("s_waitcnt vmcnt(8)" ::: "memory");
    } else if (k == 30) {
      asm volatile("s_waitcnt vmcnt(4)" ::: "memory");
    } else {
      asm volatile("s_waitcnt vmcnt(0)" ::: "memory");
    }
    __builtin_amdgcn_sched_barrier(0);
    __builtin_amdgcn_s_barrier();
    const int cur = k % 3;
    s16x8 a[4], b[4];
#pragma unroll
    for (int mi = 0; mi < 4; ++mi)
      a[mi] = *(const s16x8*)&As[cur][(wr * 64 + mi * 16 + lr) * 32 + csw];
#pragma unroll
    for (int nj = 0; nj < 4; ++nj)
      b[nj] = *(const s16x8*)&Bs[cur][(wc * 64 + nj * 16 + lr) * 32 + csw];
#pragma unroll
    for (int mi = 0; mi < 4; ++mi)
#pragma unroll
      for (int nj = 0; nj < 4; ++nj)
        acc[mi][nj] = MFMA(a[mi], b[nj], acc[mi][nj]);
    __builtin_amdgcn_s_barrier();
    if (k < 29) QKV_STAGE(cur, (k + 3) * 32);
  }
#undef QKV_STAGE

  const float QSCALE = 0.125f * 1.44269504f;
  for (int mi = 0; mi < 4; ++mi) {
    for (int nj = 0; nj < 4; ++nj) {
      const int n_g = n0 + wc * 64 + nj * 16 + lr;
      const int buf = n_g >> 10;       // 0=Q 1=K 2=V
      const int col = n_g & 1023;
      const int h = col >> 6, d = col & 63;
      u16* dst = (buf == 0) ? Qh : ((buf == 1) ? Kh : Vh);
      for (int r = 0; r < 4; ++r) {
        const int row = m0 + wr * 64 + mi * 16 + g * 4 + r;  // 0..4095
        const int b = row >> 11, n = row & 2047;
        const size_t off = (size_t)((b * 16 + h) * 2048 + n) * 64 + d;
        float v = acc[mi][nj][r];
        if (buf == 1) v += bf2f(Pp[off]);
        if (buf == 0) v *= QSCALE;
        dst[off] = f2bf_rte(v);
      }
    }
  }
}

// ---------------- flash attention: 4-buffer gload_lds pipeline (r20 body) ----------------
__global__ __launch_bounds__(512, 4) void k_attn(const u16* __restrict__ Qh,
                                                 const u16* __restrict__ Kh,
                                                 const u16* __restrict__ Vt,
                                                 u16* __restrict__ Oh) {
  const int t = threadIdx.x, lane = t & 63, wid = t >> 6;  // wid 0..7
  const int g = lane >> 4, lr = lane & 15;
  const int hid = blockIdx.x;
  const int lid = (hid & 7) * 64 + (hid >> 3);   // bijective XCD swizzle (512 % 8 == 0)
  const int bh = lid >> 4, itile = lid & 15;
  const int i0 = itile * 128 + wid * 16;         // this wave's 16 Q rows

  __shared__ char Ks[4][8192];
  __shared__ char Vs[4][8192];

  const u16* Qp = Qh + (size_t)bh * 2048 * 64;
  const u16* Kp = Kh + (size_t)bh * 2048 * 64;
  const u16* Vp = Vt + (size_t)bh * 64 * 2048;

  s16x8 aq[2];
  aq[0] = *(const s16x8*)&Qp[(size_t)(i0 + lr) * 64 + g * 8];
  aq[1] = *(const s16x8*)&Qp[(size_t)(i0 + lr) * 64 + 32 + g * 8];

  f32x4 oa[4] = {};
  float ms = -1e30f, ls = 0.f;

  const int srow = t >> 3;                  // 0..63
  const int sch = (t & 7) * 16;             // byte chunk in row
  const int schS = sch ^ ((srow & 7) << 4); // pre-swizzled source chunk
  const u16* kB = &Kp[(size_t)srow * 64 + (schS >> 1)];
  const u16* vB = &Vp[(size_t)srow * 2048 + (schS >> 1)];

#define ATTN_STAGE(p)                                                \
  {                                                                  \
    gload16(kB + (size_t)(p) * 4096, (u16*)Ks[(p) & 3] + wid * 512); \
    gload16(vB + (size_t)(p) * 64, (u16*)Vs[(p) & 3] + wid * 512);   \
  }

#define ATTN_BODY(BUF)                                                         \
  {                                                                            \
    const char* Kc = Ks[BUF];                                                  \
    const char* Vc = Vs[BUF];                                                  \
    f32x4 s[4] = {};                                                           \
    _Pragma("unroll") for (int jf = 0; jf < 4; ++jf) {                         \
      const int row = jf * 16 + lr;                                            \
      const int bw = (row & 7) << 4;                                           \
      s16x8 bk0 = *(const s16x8*)(Kc + ((row * 128 + g * 16) ^ bw));           \
      s16x8 bk1 = *(const s16x8*)(Kc + ((row * 128 + 64 + g * 16) ^ bw));      \
      s[jf] = MFMA(bk0, aq[0], s[jf]);                                         \
      s[jf] = MFMA(bk1, aq[1], s[jf]);                                         \
    }                                                                          \
    float mj[4];                                                               \
    _Pragma("unroll") for (int jf = 0; jf < 4; ++jf)                           \
        mj[jf] = fmaxf(fmaxf(s[jf][0], s[jf][1]), fmaxf(s[jf][2], s[jf][3]));  \
    float tl = fmaxf(fmaxf(mj[0], mj[1]), fmaxf(mj[2], mj[3]));                \
    if (!__all(tl <= ms + 8.f)) {                                              \
      float tm = fmaxf(tl, __shfl_xor(tl, 16, 64));                            \
      tm = fmaxf(tm, __shfl_xor(tm, 32, 64));                                  \
      float mn = fmaxf(ms, tm);                                                \
      float al = __builtin_amdgcn_exp2f(ms - mn);                              \
      ls *= al;                                                                \
      ms = mn;                                                                 \
      _Pragma("unroll") for (int r = 0; r < 4; ++r) {                          \
        float ab = __shfl(al, g * 4 + r, 64);                                  \
        _Pragma("unroll") for (int df = 0; df < 4; ++df) oa[df][r] *= ab;      \
      }                                                                        \
    }                                                                          \
    float pj[4];                                                               \
    _Pragma("unroll") for (int jf = 0; jf < 4; ++jf) {                         \
      _Pragma("unroll") for (int r = 0; r < 4; ++r)                            \
          s[jf][r] = __builtin_amdgcn_exp2f(s[jf][r] - ms);                    \
      pj[jf] = (s[jf][0] + s[jf][1]) + (s[jf][2] + s[jf][3]);                  \
    }                                                                          \
    ls += (pj[0] + pj[1]) + (pj[2] + pj[3]);                                   \
    u32 pk[4][2];                                                              \
    _Pragma("unroll") for (int jf = 0; jf < 4; ++jf) {                         \
      asm("v_cvt_pk_bf16_f32 %0, %1, %2"                                       \
          : "=v"(pk[jf][0]) : "v"(s[jf][0]), "v"(s[jf][1]));                   \
      asm("v_cvt_pk_bf16_f32 %0, %1, %2"                                       \
          : "=v"(pk[jf][1]) : "v"(s[jf][2]), "v"(s[jf][3]));                   \
    }                                                                          \
    s16x8 pa[2];                                                               \
    _Pragma("unroll") for (int c = 0; c < 2; ++c) {                            \
      u32 w_[4];                                                               \
      _Pragma("unroll") for (int wl = 0; wl < 2; ++wl) {                       \
        u32 A = pk[2 * c][wl], B = pk[2 * c + 1][wl];                          \
        asm("v_permlane32_swap_b32 %0, %1" : "+v"(A), "+v"(B));                \
        asm("v_permlane16_swap_b32 %0, %1" : "+v"(A), "+v"(B));                \
        w_[wl] = A;                                                            \
        w_[2 + wl] = B;                                                        \
      }                                                                        \
      __builtin_memcpy(&pa[c], w_, 16);                                        \
    }                                                                          \
    _Pragma("unroll") for (int df = 0; df < 4; ++df) {                         \
      const int row = df * 16 + lr;                                            \
      const int bw = (row & 7) << 4;                                           \
      s16x8 bv0 = *(const s16x8*)(Vc + ((row * 128 + g * 16) ^ bw));           \
      s16x8 bv1 = *(const s16x8*)(Vc + ((row * 128 + 64 + g * 16) ^ bw));      \
      oa[df] = MFMA(pa[0], bv0, oa[df]);                                       \
      oa[df] = MFMA(pa[1], bv1, oa[df]);                                       \
    }                                                                          \
  }

  ATTN_STAGE(0);
  ATTN_STAGE(1);
  ATTN_STAGE(2);

  for (int tb = 0; tb < 7; ++tb) {
#pragma unroll
    for (int ti = 0; ti < 4; ++ti) {
      const int tt = tb * 4 + ti;
      asm volatile("s_waitcnt vmcnt(4)" ::: "memory");
      __builtin_amdgcn_sched_barrier(0);
      __builtin_amdgcn_s_barrier();
      ATTN_STAGE(tt + 3);
      ATTN_BODY(ti);
    }
  }
  {
    asm volatile("s_waitcnt vmcnt(4)" ::: "memory");
    __builtin_amdgcn_sched_barrier(0);
    __builtin_amdgcn_s_barrier();
    ATTN_STAGE(31);
    ATTN_BODY(0);
  }
  {
    asm volatile("s_waitcnt vmcnt(4)" ::: "memory");
    __builtin_amdgcn_sched_barrier(0);
    __builtin_amdgcn_s_barrier();
    ATTN_BODY(1);
  }
  {
    asm volatile("s_waitcnt vmcnt(2)" ::: "memory");
    __builtin_amdgcn_sched_barrier(0);
    __builtin_amdgcn_s_barrier();
    ATTN_BODY(2);
  }
  {
    asm volatile("s_waitcnt vmcnt(0)" ::: "memory");
    __builtin_amdgcn_sched_barrier(0);
    __builtin_amdgcn_s_barrier();
    ATTN_BODY(3);
  }
#undef ATTN_BODY
#undef ATTN_STAGE

  ls += __shfl_xor(ls, 16, 64);
  ls += __shfl_xor(ls, 32, 64);
  float lb[4];
#pragma unroll
  for (int r = 0; r < 4; ++r) lb[r] = __shfl(ls, g * 4 + r, 64);

  u16* Op = Oh + (size_t)bh * 2048 * 64;
#pragma unroll
  for (int df = 0; df < 4; ++df)
#pragma unroll
    for (int r = 0; r < 4; ++r) {
      const int row0 = i0 + g * 4 + r;
      Op[(size_t)row0 * 64 + df * 16 + lr] = f2bf_rte(oa[df][r] / lb[r]);
    }
}

// ---------------- out GEMM: 3-buffer pipeline; bf16 residual; bf16 X out ----------------
__global__ __launch_bounds__(256) void k_out_gemm(const u16* __restrict__ Oh,
                                                  const u16* __restrict__ WTo,
                                                  const float* __restrict__ bo,
                                                  const u16* __restrict__ qsb,
                                                  u16* __restrict__ X) {
  __shared__ u16 As[3][4096];
  __shared__ u16 Bs[3][4096];
  const int t = threadIdx.x;
  const int lane = t & 63, wid = t >> 6;
  const int wr = wid >> 1, wc = wid & 1;
  const int g = lane >> 4, lr = lane & 15;
  const int lin = blockIdx.y * 8 + blockIdx.x;
  const int swz = (lin & 7) * 32 + (lin >> 3);
  const int m0 = (swz / 8) * 128, n0 = (swz % 8) * 128;

  const int srcRow = t >> 2;
  const int srcKsw = ((t & 3) * 8) ^ (((t >> 3) & 3) << 3);
  const int rg = m0 + srcRow, bb0 = rg >> 11, nn0 = rg & 2047;
  const int rg2 = rg + 64, bb2 = rg2 >> 11, nn2 = rg2 & 2047;
  const u16* bSrc = &WTo[(size_t)(n0 + srcRow) * 1024 + srcKsw];
  const int csw = (g * 8) ^ (((lr >> 1) & 3) << 3);

  f32x4 acc[4][4] = {};

#define OUT_STAGE(buf, k0)                                                        \
  {                                                                               \
    const int h_ = (k0) >> 6, d_ = ((k0) & 63) + srcKsw;                          \
    gload16(&Oh[((size_t)(bb0 * 16 + h_) * 2048 + nn0) * 64 + d_],                \
            &As[buf][wid * 512]);                                                 \
    gload16(&Oh[((size_t)(bb2 * 16 + h_) * 2048 + nn2) * 64 + d_],                \
            &As[buf][wid * 512 + 2048]);                                          \
    gload16(bSrc + (k0), &Bs[buf][wid * 512]);                                    \
    gload16(bSrc + 65536 + (k0), &Bs[buf][wid * 512 + 2048]);                     \
  }

  OUT_STAGE(0, 0);
  OUT_STAGE(1, 32);
  OUT_STAGE(2, 64);
  for (int k = 0; k < 32; ++k) {
    if (k < 30) {
      asm volatile("s_waitcnt vmcnt(8)" ::: "memory");
    } else if (k == 30) {
      asm volatile("s_waitcnt vmcnt(4)" ::: "memory");
    } else {
      asm volatile("s_waitcnt vmcnt(0)" ::: "memory");
    }
    __builtin_amdgcn_sched_barrier(0);
    __builtin_amdgcn_s_barrier();
    const int cur = k % 3;
    s16x8 a[4], b[4];
#pragma unroll
    for (int mi = 0; mi < 4; ++mi)
      a[mi] = *(const s16x8*)&As[cur][(wr * 64 + mi * 16 + lr) * 32 + csw];
#pragma unroll
    for (int nj = 0; nj < 4; ++nj)
      b[nj] = *(const s16x8*)&Bs[cur][(wc * 64 + nj * 16 + lr) * 32 + csw];
#pragma unroll
    for (int mi = 0; mi < 4; ++mi)
#pragma unroll
      for (int nj = 0; nj < 4; ++nj)
        acc[mi][nj] = MFMA(a[mi], b[nj], acc[mi][nj]);
    __builtin_amdgcn_s_barrier();
    if (k < 29) OUT_STAGE(cur, (k + 3) * 32);
  }
#undef OUT_STAGE

  for (int mi = 0; mi < 4; ++mi) {
    for (int nj = 0; nj < 4; ++nj) {
      const int col = n0 + wc * 64 + nj * 16 + lr;
      for (int r = 0; r < 4; ++r) {
        const int row = m0 + wr * 64 + mi * 16 + g * 4 + r;
        float v = acc[mi][nj][r] + bo[col] + bf2f(qsb[(size_t)row * 1024 + col]);
        X[(size_t)row * 1024 + col] = f2bf_rte(v);
      }
    }
  }
}

// ---------------- LayerNorm rows of 1024 (bf16 in, f32 out) ----------------
__global__ __launch_bounds__(256) void k_ln(const u16* __restrict__ X,
                                            const float* __restrict__ gg,
                                            const float* __restrict__ bb,
                                            float* __restrict__ out) {
  const int row = blockIdx.x, t = threadIdx.x;
  const int wid = t >> 6, lane = t & 63;
  const u16* xr = X + (size_t)row * 1024;
  s16x4 xv = *(const s16x4*)&xr[t * 4];
  float x[4];
  for (int i = 0; i < 4; ++i) x[i] = bf2f((u16)xv[i]);
  float s1 = (x[0] + x[1]) + (x[2] + x[3]);
  float s2 = (x[0] * x[0] + x[1] * x[1]) + (x[2] * x[2] + x[3] * x[3]);
  for (int off = 32; off > 0; off >>= 1) {
    s1 += __shfl_down(s1, off, 64);
    s2 += __shfl_down(s2, off, 64);
  }
  __shared__ float red[2][4];
  if (lane == 0) { red[0][wid] = s1; red[1][wid] = s2; }
  __syncthreads();
  s1 = red[0][0] + red[0][1] + red[0][2] + red[0][3];
  s2 = red[1][0] + red[1][1] + red[1][2] + red[1][3];
  const float mu = s1 * (1.f / 1024.f);
  const float var = s2 * (1.f / 1024.f) - mu * mu;
  const float rstd = rsqrtf(var + 1e-5f);
  f32x4 gv = *(const f32x4*)&gg[t * 4];
  f32x4 bv = *(const f32x4*)&bb[t * 4];
  f32x4 ov;
  for (int i = 0; i < 4; ++i) ov[i] = (x[i] - mu) * rstd * gv[i] + bv[i];
  *(f32x4*)&out[(size_t)row * 1024 + t * 4] = ov;
}

extern "C" void kernel_launch(void* const* d_in, const int* in_sizes, int n_in,
                              void* d_out, int out_size, void* d_ws, size_t ws_size,
                              hipStream_t stream) {
  (void)in_sizes; (void)n_in; (void)out_size; (void)ws_size;
  const float* q_s = (const float*)d_in[0];
  const float* pos = (const float*)d_in[1];
  const float* Wq = (const float*)d_in[2];
  const float* Wk = (const float*)d_in[3];
  const float* Wv = (const float*)d_in[4];
  const float* Wo = (const float*)d_in[5];
  const float* bo = (const float*)d_in[6];
  const float* lng = (const float*)d_in[7];
  const float* lnb = (const float*)d_in[8];
  float* out = (float*)d_out;

  u16* ws = (u16*)d_ws;
  const size_t MB1 = 1024 * 1024;  // elements
  u16* WT  = ws;                   // 4 x 1M bf16 (Wq^T,Wk^T,Wv^T,Wo^T)
  u16* Xbf = ws + 4 * MB1;         // q_s as bf16
  u16* Qh  = Xbf + 4 * MB1;        // [32][2048][64]
  u16* Kh  = Qh + 4 * MB1;
  u16* Vh  = Kh + 4 * MB1;
  u16* Vt  = Vh + 4 * MB1;         // [32][64][2048]
  u16* Oh  = Vt + 4 * MB1;         // [32][2048][64]
  u16* Pp  = Oh;                   // bf16 packed pos, aliases Oh (dead until attn)
  u16* Xb  = Qh;                   // bf16 pre-LN x, aliases Qh (dead after attn)

  dim3 blk(256);
  k_prep<<<dim3(4096), blk, 0, stream>>>(q_s, pos, Wq, Wk, Wv, Wo, Xbf, Pp, WT);
  k_qkv_gemm<<<dim3(24, 32), blk, 0, stream>>>(Xbf, WT, Pp, Qh, Kh, Vh);
  k_transpose_v<<<dim3(32, 32), blk, 0, stream>>>(Vh, Vt);
  k_attn<<<dim3(512), dim3(512), 0, stream>>>(Qh, Kh, Vt, Oh);
  k_out_gemm<<<dim3(8, 32), blk, 0, stream>>>(Oh, WT + 3 * MB1, bo, Xbf, Xb);
  k_ln<<<4096, blk, 0, stream>>>(Xb, lng, lnb, out);
}